// Round 4
// baseline (137.891 us; speedup 1.0000x reference)
//
#include <hip/hip_runtime.h>
#include <hip/hip_bf16.h>

// ---------------------------------------------------------------------------
// Gaussian splatting forward render, fp32. Tile-based, 3 launches.
// K1 k_pre:    per-gaussian preprocess -> pre[11*N] SoA (incl. conservative
//              cull radius)
// K2 k_ranksc: fused stable rank sort (depth asc, O(N^2), LDS-tiled, one
//              thread per gaussian, no atomics) + scatter into depth-sorted
//              packed AoS (12 floats) + bbox[]
// K3 k_render: 1 block per 8x8 pixel tile (512 thr = 8 waves).
//              Phase 1: ballot-compact the tile's gaussian list (sorted
//              order preserved) into LDS using conservative bboxes (exact
//              cull: outside bbox => alpha < 1/255 => contribution == 0).
//              Phase 2: 8 waves composite 8 depth segments branchlessly,
//              then exact log-depth combine across segments in LDS.
// Measured context (R3): harness re-poison of the 256 MiB d_ws dominates
// dur_us (~84 us fixed, memory-bound fillBuffer); our dispatches are ~6 us.
// ---------------------------------------------------------------------------

__global__ void k_pre(const float* __restrict__ means, const float* __restrict__ quats,
                      const float* __restrict__ scales, const float* __restrict__ opacs,
                      const float* __restrict__ colors, const float* __restrict__ ct,
                      const float* __restrict__ Kmat, int N,
                      float* __restrict__ pre) {
  int i = blockIdx.x * blockDim.x + threadIdx.x;
  if (i >= N) return;

  // camtoworld (rigid) -> viewmat: Rw = Rc^T, tw = -Rc^T * tc
  float c00 = ct[0], c01 = ct[1], c02 = ct[2], c03 = ct[3];
  float c10 = ct[4], c11 = ct[5], c12 = ct[6], c13 = ct[7];
  float c20 = ct[8], c21 = ct[9], c22 = ct[10], c23 = ct[11];
  float W00 = c00, W01 = c10, W02 = c20;
  float W10 = c01, W11 = c11, W12 = c21;
  float W20 = c02, W21 = c12, W22 = c22;
  float tw0 = -(W00 * c03 + W01 * c13 + W02 * c23);
  float tw1 = -(W10 * c03 + W11 * c13 + W12 * c23);
  float tw2 = -(W20 * c03 + W21 * c13 + W22 * c23);
  float fx = Kmat[0], cx = Kmat[2], fy = Kmat[4], cy = Kmat[5];

  float mx = means[3 * i], my = means[3 * i + 1], mz = means[3 * i + 2];
  float tx = W00 * mx + W01 * my + W02 * mz + tw0;
  float ty = W10 * mx + W11 * my + W12 * mz + tw1;
  float depth = W20 * mx + W21 * my + W22 * mz + tw2;
  float tz = fmaxf(depth, 0.01f);
  float z1 = 1.0f / tz;
  float u = fx * tx * z1 + cx;
  float v = fy * ty * z1 + cy;

  // quaternion -> rotation
  float qw = quats[4 * i], qx = quats[4 * i + 1], qy = quats[4 * i + 2], qz = quats[4 * i + 3];
  float qn = rsqrtf(qw * qw + qx * qx + qy * qy + qz * qz);
  qw *= qn; qx *= qn; qy *= qn; qz *= qn;
  float sx = expf(scales[3 * i]), sy = expf(scales[3 * i + 1]), sz = expf(scales[3 * i + 2]);
  float r00 = 1.f - 2.f * (qy * qy + qz * qz);
  float r01 = 2.f * (qx * qy - qw * qz);
  float r02 = 2.f * (qx * qz + qw * qy);
  float r10 = 2.f * (qx * qy + qw * qz);
  float r11 = 1.f - 2.f * (qx * qx + qz * qz);
  float r12 = 2.f * (qy * qz - qw * qx);
  float r20 = 2.f * (qx * qz - qw * qy);
  float r21 = 2.f * (qy * qz + qw * qx);
  float r22 = 1.f - 2.f * (qx * qx + qy * qy);
  float m00 = r00 * sx, m01 = r01 * sy, m02 = r02 * sz;
  float m10 = r10 * sx, m11 = r11 * sy, m12 = r12 * sz;
  float m20 = r20 * sx, m21 = r21 * sy, m22 = r22 * sz;
  float S00 = m00 * m00 + m01 * m01 + m02 * m02;
  float S01 = m00 * m10 + m01 * m11 + m02 * m12;
  float S02 = m00 * m20 + m01 * m21 + m02 * m22;
  float S11 = m10 * m10 + m11 * m11 + m12 * m12;
  float S12 = m10 * m20 + m11 * m21 + m12 * m22;
  float S22 = m20 * m20 + m21 * m21 + m22 * m22;
  float A00 = W00 * S00 + W01 * S01 + W02 * S02;
  float A01 = W00 * S01 + W01 * S11 + W02 * S12;
  float A02 = W00 * S02 + W01 * S12 + W02 * S22;
  float A10 = W10 * S00 + W11 * S01 + W12 * S02;
  float A11 = W10 * S01 + W11 * S11 + W12 * S12;
  float A12 = W10 * S02 + W11 * S12 + W12 * S22;
  float A20 = W20 * S00 + W21 * S01 + W22 * S02;
  float A21 = W20 * S01 + W21 * S11 + W22 * S12;
  float A22 = W20 * S02 + W21 * S12 + W22 * S22;
  float V00 = A00 * W00 + A01 * W01 + A02 * W02;
  float V01 = A00 * W10 + A01 * W11 + A02 * W12;
  float V02 = A00 * W20 + A01 * W21 + A02 * W22;
  float V11 = A10 * W10 + A11 * W11 + A12 * W12;
  float V12 = A10 * W20 + A11 * W21 + A12 * W22;
  float V22 = A20 * W20 + A21 * W21 + A22 * W22;
  float j00 = fx * z1, j02 = -fx * tx * z1 * z1;
  float j11 = fy * z1, j12 = -fy * ty * z1 * z1;
  float g2_00 = j00 * j00 * V00 + 2.f * j00 * j02 * V02 + j02 * j02 * V22;
  float g2_01 = j00 * j11 * V01 + j00 * j12 * V02 + j02 * j11 * V12 + j02 * j12 * V22;
  float g2_11 = j11 * j11 * V11 + 2.f * j11 * j12 * V12 + j12 * j12 * V22;
  float a2 = g2_00 + 0.3f;
  float cc2 = g2_11 + 0.3f;
  float b2 = g2_01;
  float det = a2 * cc2 - b2 * b2;
  float idet = 1.0f / det;
  float conA = cc2 * idet, conB = -b2 * idet, conC = a2 * idet;

  float op = 1.0f / (1.0f + __expf(-opacs[i]));
  if (!(depth > 0.01f)) op = 0.0f;  // fold visibility: alpha -> 0 exactly

  // conservative cull radius: outside r, sigma > log(255*op) guaranteed
  // => reference alpha < 1/255 => contribution exactly 0.
  float lt = logf(255.f * op);                       // op==0 -> -inf
  float lam = 0.5f * (a2 + cc2) +
              sqrtf(0.25f * (a2 - cc2) * (a2 - cc2) + b2 * b2);  // lambda_max
  float rad = (lt > 0.f) ? (sqrtf(2.02f * lam * lt) + 1.0f) : 0.f;

  // SH eval (degree 3)
  float dxm = mx - c03, dym = my - c13, dzm = mz - c23;
  float dn = rsqrtf(dxm * dxm + dym * dym + dzm * dzm);
  float x = dxm * dn, y = dym * dn, z = dzm * dn;
  float xx = x * x, yy = y * y, zz = z * z;
  float xy = x * y, yz = y * z, xz = x * z;
  float k[16];
  k[0] = 0.28209479177387814f;
  k[1] = -0.4886025119029199f * y;
  k[2] = 0.4886025119029199f * z;
  k[3] = -0.4886025119029199f * x;
  k[4] = 1.0925484305920792f * xy;
  k[5] = -1.0925484305920792f * yz;
  k[6] = 0.31539156525252005f * (2.f * zz - xx - yy);
  k[7] = -1.0925484305920792f * xz;
  k[8] = 0.5462742152960396f * (xx - yy);
  k[9]  = -0.5900435899266435f * y * (3.f * xx - yy);
  k[10] = 2.890611442640554f * xy * z;
  k[11] = -0.4570457994644658f * y * (4.f * zz - xx - yy);
  k[12] = 0.3731763325901154f * z * (2.f * zz - 3.f * xx - 3.f * yy);
  k[13] = -0.4570457994644658f * x * (4.f * zz - xx - yy);
  k[14] = 1.445305721320277f * z * (xx - yy);
  k[15] = -0.5900435899266435f * x * (xx - 3.f * yy);
  float rr = 0.f, gg = 0.f, bb = 0.f;
  const float* col = colors + (size_t)i * 48;
#pragma unroll
  for (int j = 0; j < 16; ++j) {
    rr += k[j] * col[3 * j];
    gg += k[j] * col[3 * j + 1];
    bb += k[j] * col[3 * j + 2];
  }
  rr = fmaxf(rr + 0.5f, 0.f);
  gg = fmaxf(gg + 0.5f, 0.f);
  bb = fmaxf(bb + 0.5f, 0.f);

  pre[0 * N + i] = depth;
  pre[1 * N + i] = u;
  pre[2 * N + i] = v;
  pre[3 * N + i] = 0.5f * conA;  // fold sigma's 0.5 (exact)
  pre[4 * N + i] = conB;
  pre[5 * N + i] = 0.5f * conC;
  pre[6 * N + i] = op;
  pre[7 * N + i] = rr;
  pre[8 * N + i] = gg;
  pre[9 * N + i] = bb;
  pre[10 * N + i] = rad;
}

// Fused stable rank + scatter. One thread per gaussian i; LDS-tiles all N
// depths; rank_i = #{ j : d_j < d_i or (d_j == d_i and j < i) } (matches
// jnp.argsort stable order); then scatters record + bbox at slot rank_i.
// Ranks form a permutation, so every sorted slot is written exactly once.
__global__ void k_ranksc(const float* __restrict__ pre, int N,
                         float* __restrict__ srt, float4* __restrict__ bbox) {
  __shared__ float sd[256];
  int i = blockIdx.x * 256 + threadIdx.x;
  float di = (i < N) ? pre[i] : 0.f;
  int cnt = 0;
  for (int c0 = 0; c0 < N; c0 += 256) {
    int j = c0 + threadIdx.x;
    sd[threadIdx.x] = (j < N) ? pre[j] : 0.f;
    __syncthreads();
    int lim = min(256, N - c0);
    for (int jj = 0; jj < lim; ++jj) {
      float dj = sd[jj];
      int gj = c0 + jj;
      cnt += (dj < di || (dj == di && gj < i)) ? 1 : 0;
    }
    __syncthreads();
  }
  if (i >= N) return;
  float* dst = srt + (size_t)cnt * 12;
#pragma unroll
  for (int f = 0; f < 9; ++f) dst[f] = pre[(f + 1) * N + i];
  float u = pre[1 * N + i], v = pre[2 * N + i], rad = pre[10 * N + i];
  bbox[cnt] = make_float4(u - rad, v - rad, u + rad, v + rad);
}

// One block per 8x8 pixel tile. 512 threads = 8 waves.
__global__ __launch_bounds__(512) void k_render(const float* __restrict__ srt,
                                                const float4* __restrict__ bbox, int N,
                                                float* __restrict__ out, int Wimg,
                                                int tilesX, int P) {
  __shared__ int lst[2048];
  __shared__ float red[8][5][64];
  __shared__ int wcnt[8];

  int t = threadIdx.x;
  int lane = t & 63;
  int w = __builtin_amdgcn_readfirstlane(t >> 6);
  int tile = blockIdx.x;
  int tx = tile % tilesX, ty = tile / tilesX;
  float x0 = tx * 8 + 0.5f, x1 = tx * 8 + 7.5f;
  float y0 = ty * 8 + 0.5f, y1 = ty * 8 + 7.5f;

  // ---- Phase 1: build this tile's gaussian list (sorted order preserved) ----
  int base = 0;
  for (int c0 = 0; c0 < N; c0 += 512) {
    int g = c0 + t;
    bool keep = false;
    if (g < N) {
      float4 bb = bbox[g];
      keep = (bb.x <= x1) & (bb.z >= x0) & (bb.y <= y1) & (bb.w >= y0);
    }
    unsigned long long m = __ballot(keep);
    if (lane == 0) wcnt[w] = __popcll(m);
    __syncthreads();
    int woff = base;
    for (int k = 0; k < w; ++k) woff += wcnt[k];
    int tot = 0;
#pragma unroll
    for (int k = 0; k < 8; ++k) tot += wcnt[k];
    if (keep) lst[woff + __popcll(m & ((1ull << lane) - 1ull))] = g;
    base += tot;
    __syncthreads();
  }
  int cnt = base;

  // ---- Phase 2: 8 waves composite 8 depth segments, branchless ----
  float gx = tx * 8 + (lane & 7) + 0.5f;
  float gy = ty * 8 + (lane >> 3) + 0.5f;
  int chunk = (cnt + 7) >> 3;
  int g0 = w * chunk;
  int g1 = min(cnt, g0 + chunk);

  const float4* s4 = (const float4*)srt;
  float T = 1.0f, accr = 0.f, accg = 0.f, accb = 0.f, acca = 0.f;
  for (int g = g0; g < g1; ++g) {
    int idx = lst[g];
    float4 a = s4[idx * 3 + 0];  // u, v, A_half, B
    float4 b = s4[idx * 3 + 1];  // C_half, op, r, g
    float4 c = s4[idx * 3 + 2];  // b, pad, pad, pad
    float dx = gx - a.x, dy = gy - a.y;
    float s = a.z * dx * dx + b.x * dy * dy + a.w * dx * dy;
    float e = __expf(-fmaxf(s, 0.f));
    float al = b.y * e;
    al = (al >= 0.00392156862745098f) ? fminf(al, 0.999f) : 0.f;  // exact cull
    float wgt = al * T;
    accr = fmaf(wgt, b.z, accr);
    accg = fmaf(wgt, b.w, accg);
    accb = fmaf(wgt, c.x, accb);
    acca += wgt;
    T *= 1.f - al;
  }
  red[w][0][lane] = accr;
  red[w][1][lane] = accg;
  red[w][2][lane] = accb;
  red[w][3][lane] = acca;
  red[w][4][lane] = T;
  __syncthreads();

  // ---- exact combine across the 8 ordered segments ----
  if (t < 64) {
    float Tr = 1.f, R = 0.f, G = 0.f, B = 0.f, A = 0.f;
#pragma unroll
    for (int k = 0; k < 8; ++k) {
      R += Tr * red[k][0][t];
      G += Tr * red[k][1][t];
      B += Tr * red[k][2][t];
      A += Tr * red[k][3][t];
      Tr *= red[k][4][t];
    }
    int pix = (ty * 8 + (t >> 3)) * Wimg + tx * 8 + (t & 7);
    out[pix * 3 + 0] = R;
    out[pix * 3 + 1] = G;
    out[pix * 3 + 2] = B;
    out[(size_t)P * 3 + pix] = A;
  }
}

extern "C" void kernel_launch(void* const* d_in, const int* in_sizes, int n_in,
                              void* d_out, int out_size, void* d_ws, size_t ws_size,
                              hipStream_t stream) {
  const float* means  = (const float*)d_in[0];
  const float* quats  = (const float*)d_in[1];
  const float* scales = (const float*)d_in[2];
  const float* opacs  = (const float*)d_in[3];
  const float* colors = (const float*)d_in[4];
  const float* ct     = (const float*)d_in[5];
  const float* Kmat   = (const float*)d_in[6];

  int N = in_sizes[0] / 3;       // means is (N,3)
  int P = out_size / 4;          // 3*H*W colors + H*W alphas
  int Wimg = 128;                // harness-fixed (W==H, P=W*H)
  int Himg = P / Wimg;
  int tilesX = Wimg / 8, tilesY = Himg / 8;

  float*  pre  = (float*)d_ws;                        // 11*N floats
  float*  srt  = pre + (size_t)11 * N;                // 12*N floats (48B AoS)
  float4* bbox = (float4*)(srt + (size_t)12 * N);     // N float4

  int nb = (N + 255) / 256;
  k_pre<<<nb, 256, 0, stream>>>(means, quats, scales, opacs, colors, ct, Kmat, N, pre);
  k_ranksc<<<nb, 256, 0, stream>>>(pre, N, srt, bbox);
  k_render<<<tilesX * tilesY, 512, 0, stream>>>(srt, bbox, N, (float*)d_out, Wimg, tilesX, P);
}

// Round 5
// 86.595 us; speedup vs baseline: 1.5924x; 1.5924x over previous
//
#include <hip/hip_runtime.h>
#include <hip/hip_bf16.h>

// ---------------------------------------------------------------------------
// Gaussian splatting forward render, fp32. Tile-based, 4 launches.
// (R4 post-mortem: fusing rank+scatter into 8 blocks was latency-bound at
//  0.34% occupancy, 59.8 us. Reverted to the R3 split; rank j-parallelism
//  widened to grid (nb,32) so no dispatch exceeds ~2 us.)
// K1 k_pre:    per-gaussian preprocess -> pre[11*N] SoA (incl. conservative
//              cull radius), zero rank[]; colors read as float4.
// K2 k_rank:   O(N^2) stable rank (depth asc), grid (nb,32): 256 blocks,
//              64 compares/thread, one atomicAdd per thread.
// K3 k_scatter: gather into depth-sorted packed AoS (12 floats) + bbox[].
// K4 k_render: 1 block per 8x8 pixel tile (512 thr = 8 waves).
//              Phase 1: ballot-compact tile list (sorted order preserved)
//              via conservative bboxes (exact cull: outside bbox =>
//              alpha < 1/255 => contribution == 0).
//              Phase 2: 8 waves composite 8 depth segments branchlessly,
//              then exact log-depth combine across segments in LDS.
// Measured context (R3): harness re-poison of the 256 MiB d_ws dominates
// dur_us (~84 us fixed, memory-bound fillBuffer); our dispatches are ~6 us.
// ---------------------------------------------------------------------------

__global__ void k_pre(const float* __restrict__ means, const float* __restrict__ quats,
                      const float* __restrict__ scales, const float* __restrict__ opacs,
                      const float* __restrict__ colors, const float* __restrict__ ct,
                      const float* __restrict__ Kmat, int N,
                      float* __restrict__ pre, int* __restrict__ rank) {
  int i = blockIdx.x * blockDim.x + threadIdx.x;
  if (i >= N) return;
  rank[i] = 0;

  // camtoworld (rigid) -> viewmat: Rw = Rc^T, tw = -Rc^T * tc
  float c00 = ct[0], c01 = ct[1], c02 = ct[2], c03 = ct[3];
  float c10 = ct[4], c11 = ct[5], c12 = ct[6], c13 = ct[7];
  float c20 = ct[8], c21 = ct[9], c22 = ct[10], c23 = ct[11];
  float W00 = c00, W01 = c10, W02 = c20;
  float W10 = c01, W11 = c11, W12 = c21;
  float W20 = c02, W21 = c12, W22 = c22;
  float tw0 = -(W00 * c03 + W01 * c13 + W02 * c23);
  float tw1 = -(W10 * c03 + W11 * c13 + W12 * c23);
  float tw2 = -(W20 * c03 + W21 * c13 + W22 * c23);
  float fx = Kmat[0], cx = Kmat[2], fy = Kmat[4], cy = Kmat[5];

  float mx = means[3 * i], my = means[3 * i + 1], mz = means[3 * i + 2];
  float tx = W00 * mx + W01 * my + W02 * mz + tw0;
  float ty = W10 * mx + W11 * my + W12 * mz + tw1;
  float depth = W20 * mx + W21 * my + W22 * mz + tw2;
  float tz = fmaxf(depth, 0.01f);
  float z1 = 1.0f / tz;
  float u = fx * tx * z1 + cx;
  float v = fy * ty * z1 + cy;

  // quaternion -> rotation
  float qw = quats[4 * i], qx = quats[4 * i + 1], qy = quats[4 * i + 2], qz = quats[4 * i + 3];
  float qn = rsqrtf(qw * qw + qx * qx + qy * qy + qz * qz);
  qw *= qn; qx *= qn; qy *= qn; qz *= qn;
  float sx = expf(scales[3 * i]), sy = expf(scales[3 * i + 1]), sz = expf(scales[3 * i + 2]);
  float r00 = 1.f - 2.f * (qy * qy + qz * qz);
  float r01 = 2.f * (qx * qy - qw * qz);
  float r02 = 2.f * (qx * qz + qw * qy);
  float r10 = 2.f * (qx * qy + qw * qz);
  float r11 = 1.f - 2.f * (qx * qx + qz * qz);
  float r12 = 2.f * (qy * qz - qw * qx);
  float r20 = 2.f * (qx * qz - qw * qy);
  float r21 = 2.f * (qy * qz + qw * qx);
  float r22 = 1.f - 2.f * (qx * qx + qy * qy);
  float m00 = r00 * sx, m01 = r01 * sy, m02 = r02 * sz;
  float m10 = r10 * sx, m11 = r11 * sy, m12 = r12 * sz;
  float m20 = r20 * sx, m21 = r21 * sy, m22 = r22 * sz;
  float S00 = m00 * m00 + m01 * m01 + m02 * m02;
  float S01 = m00 * m10 + m01 * m11 + m02 * m12;
  float S02 = m00 * m20 + m01 * m21 + m02 * m22;
  float S11 = m10 * m10 + m11 * m11 + m12 * m12;
  float S12 = m10 * m20 + m11 * m21 + m12 * m22;
  float S22 = m20 * m20 + m21 * m21 + m22 * m22;
  float A00 = W00 * S00 + W01 * S01 + W02 * S02;
  float A01 = W00 * S01 + W01 * S11 + W02 * S12;
  float A02 = W00 * S02 + W01 * S12 + W02 * S22;
  float A10 = W10 * S00 + W11 * S01 + W12 * S02;
  float A11 = W10 * S01 + W11 * S11 + W12 * S12;
  float A12 = W10 * S02 + W11 * S12 + W12 * S22;
  float A20 = W20 * S00 + W21 * S01 + W22 * S02;
  float A21 = W20 * S01 + W21 * S11 + W22 * S12;
  float A22 = W20 * S02 + W21 * S12 + W22 * S22;
  float V00 = A00 * W00 + A01 * W01 + A02 * W02;
  float V01 = A00 * W10 + A01 * W11 + A02 * W12;
  float V02 = A00 * W20 + A01 * W21 + A02 * W22;
  float V11 = A10 * W10 + A11 * W11 + A12 * W12;
  float V12 = A10 * W20 + A11 * W21 + A12 * W22;
  float V22 = A20 * W20 + A21 * W21 + A22 * W22;
  float j00 = fx * z1, j02 = -fx * tx * z1 * z1;
  float j11 = fy * z1, j12 = -fy * ty * z1 * z1;
  float g2_00 = j00 * j00 * V00 + 2.f * j00 * j02 * V02 + j02 * j02 * V22;
  float g2_01 = j00 * j11 * V01 + j00 * j12 * V02 + j02 * j11 * V12 + j02 * j12 * V22;
  float g2_11 = j11 * j11 * V11 + 2.f * j11 * j12 * V12 + j12 * j12 * V22;
  float a2 = g2_00 + 0.3f;
  float cc2 = g2_11 + 0.3f;
  float b2 = g2_01;
  float det = a2 * cc2 - b2 * b2;
  float idet = 1.0f / det;
  float conA = cc2 * idet, conB = -b2 * idet, conC = a2 * idet;

  float op = 1.0f / (1.0f + __expf(-opacs[i]));
  if (!(depth > 0.01f)) op = 0.0f;  // fold visibility: alpha -> 0 exactly

  // conservative cull radius: outside r, sigma > log(255*op) guaranteed
  // => reference alpha < 1/255 => contribution exactly 0.
  float lt = logf(255.f * op);                       // op==0 -> -inf
  float lam = 0.5f * (a2 + cc2) +
              sqrtf(0.25f * (a2 - cc2) * (a2 - cc2) + b2 * b2);  // lambda_max
  float rad = (lt > 0.f) ? (sqrtf(2.02f * lam * lt) + 1.0f) : 0.f;

  // SH eval (degree 3)
  float dxm = mx - c03, dym = my - c13, dzm = mz - c23;
  float dn = rsqrtf(dxm * dxm + dym * dym + dzm * dzm);
  float x = dxm * dn, y = dym * dn, z = dzm * dn;
  float xx = x * x, yy = y * y, zz = z * z;
  float xy = x * y, yz = y * z, xz = x * z;
  float k[16];
  k[0] = 0.28209479177387814f;
  k[1] = -0.4886025119029199f * y;
  k[2] = 0.4886025119029199f * z;
  k[3] = -0.4886025119029199f * x;
  k[4] = 1.0925484305920792f * xy;
  k[5] = -1.0925484305920792f * yz;
  k[6] = 0.31539156525252005f * (2.f * zz - xx - yy);
  k[7] = -1.0925484305920792f * xz;
  k[8] = 0.5462742152960396f * (xx - yy);
  k[9]  = -0.5900435899266435f * y * (3.f * xx - yy);
  k[10] = 2.890611442640554f * xy * z;
  k[11] = -0.4570457994644658f * y * (4.f * zz - xx - yy);
  k[12] = 0.3731763325901154f * z * (2.f * zz - 3.f * xx - 3.f * yy);
  k[13] = -0.4570457994644658f * x * (4.f * zz - xx - yy);
  k[14] = 1.445305721320277f * z * (xx - yy);
  k[15] = -0.5900435899266435f * x * (xx - 3.f * yy);

  // colors: 48 contiguous floats -> 12 float4 vector loads
  const float4* col4 = (const float4*)(colors + (size_t)i * 48);
  float c[48];
#pragma unroll
  for (int j = 0; j < 12; ++j) {
    float4 q = col4[j];
    c[4 * j + 0] = q.x; c[4 * j + 1] = q.y; c[4 * j + 2] = q.z; c[4 * j + 3] = q.w;
  }
  float rr = 0.f, gg = 0.f, bb = 0.f;
#pragma unroll
  for (int j = 0; j < 16; ++j) {
    rr += k[j] * c[3 * j];
    gg += k[j] * c[3 * j + 1];
    bb += k[j] * c[3 * j + 2];
  }
  rr = fmaxf(rr + 0.5f, 0.f);
  gg = fmaxf(gg + 0.5f, 0.f);
  bb = fmaxf(bb + 0.5f, 0.f);

  pre[0 * N + i] = depth;
  pre[1 * N + i] = u;
  pre[2 * N + i] = v;
  pre[3 * N + i] = 0.5f * conA;  // fold sigma's 0.5 (exact)
  pre[4 * N + i] = conB;
  pre[5 * N + i] = 0.5f * conC;
  pre[6 * N + i] = op;
  pre[7 * N + i] = rr;
  pre[8 * N + i] = gg;
  pre[9 * N + i] = bb;
  pre[10 * N + i] = rad;
}

// stable ascending rank: rank_i = #{ j : d_j < d_i or (d_j == d_i and j < i) }
// grid (nb, 32): blockIdx.y owns a 1/32 j-chunk -> 256 blocks, 64 cmp/thread.
__global__ void k_rank(const float* __restrict__ pre, int N, int* __restrict__ rank) {
  __shared__ float sd[256];
  int i = blockIdx.x * 256 + threadIdx.x;
  float di = (i < N) ? pre[i] : 0.f;
  int chunk = (N + 31) >> 5;
  int jbase = blockIdx.y * chunk;
  int jend = min(N, jbase + chunk);
  int cnt = 0;
  for (int c0 = jbase; c0 < jend; c0 += 256) {
    int j = c0 + threadIdx.x;
    sd[threadIdx.x] = (j < jend) ? pre[j] : 0.f;
    __syncthreads();
    int lim = min(256, jend - c0);
    for (int jj = 0; jj < lim; ++jj) {
      float dj = sd[jj];
      int gj = c0 + jj;
      cnt += (dj < di || (dj == di && gj < i)) ? 1 : 0;
    }
    __syncthreads();
  }
  if (i < N && cnt > 0) atomicAdd(&rank[i], cnt);
}

// packed sorted record (12 floats): [u,v,Ah,B | Ch,op,r,g | b,-,-,-]
// plus bbox[rank] = (u-rad, v-rad, u+rad, v+rad) for the tile test.
__global__ void k_scatter(const float* __restrict__ pre, int N, const int* __restrict__ rank,
                          float* __restrict__ srt, float4* __restrict__ bbox) {
  int i = blockIdx.x * 256 + threadIdx.x;
  if (i >= N) return;
  int r = rank[i];
  float* dst = srt + (size_t)r * 12;
#pragma unroll
  for (int f = 0; f < 9; ++f) dst[f] = pre[(f + 1) * N + i];
  float u = pre[1 * N + i], v = pre[2 * N + i], rad = pre[10 * N + i];
  bbox[r] = make_float4(u - rad, v - rad, u + rad, v + rad);
}

// One block per 8x8 pixel tile. 512 threads = 8 waves.
__global__ __launch_bounds__(512) void k_render(const float* __restrict__ srt,
                                                const float4* __restrict__ bbox, int N,
                                                float* __restrict__ out, int Wimg,
                                                int tilesX, int P) {
  __shared__ int lst[2048];
  __shared__ float red[8][5][64];
  __shared__ int wcnt[8];

  int t = threadIdx.x;
  int lane = t & 63;
  int w = __builtin_amdgcn_readfirstlane(t >> 6);
  int tile = blockIdx.x;
  int tx = tile % tilesX, ty = tile / tilesX;
  float x0 = tx * 8 + 0.5f, x1 = tx * 8 + 7.5f;
  float y0 = ty * 8 + 0.5f, y1 = ty * 8 + 7.5f;

  // ---- Phase 1: build this tile's gaussian list (sorted order preserved) ----
  int base = 0;
  for (int c0 = 0; c0 < N; c0 += 512) {
    int g = c0 + t;
    bool keep = false;
    if (g < N) {
      float4 bb = bbox[g];
      keep = (bb.x <= x1) & (bb.z >= x0) & (bb.y <= y1) & (bb.w >= y0);
    }
    unsigned long long m = __ballot(keep);
    if (lane == 0) wcnt[w] = __popcll(m);
    __syncthreads();
    int woff = base;
    for (int k = 0; k < w; ++k) woff += wcnt[k];
    int tot = 0;
#pragma unroll
    for (int k = 0; k < 8; ++k) tot += wcnt[k];
    if (keep) lst[woff + __popcll(m & ((1ull << lane) - 1ull))] = g;
    base += tot;
    __syncthreads();
  }
  int cnt = base;

  // ---- Phase 2: 8 waves composite 8 depth segments, branchless ----
  float gx = tx * 8 + (lane & 7) + 0.5f;
  float gy = ty * 8 + (lane >> 3) + 0.5f;
  int chunk = (cnt + 7) >> 3;
  int g0 = w * chunk;
  int g1 = min(cnt, g0 + chunk);

  const float4* s4 = (const float4*)srt;
  float T = 1.0f, accr = 0.f, accg = 0.f, accb = 0.f, acca = 0.f;
  for (int g = g0; g < g1; ++g) {
    int idx = lst[g];
    float4 a = s4[idx * 3 + 0];  // u, v, A_half, B
    float4 b = s4[idx * 3 + 1];  // C_half, op, r, g
    float4 c = s4[idx * 3 + 2];  // b, pad, pad, pad
    float dx = gx - a.x, dy = gy - a.y;
    float s = a.z * dx * dx + b.x * dy * dy + a.w * dx * dy;
    float e = __expf(-fmaxf(s, 0.f));
    float al = b.y * e;
    al = (al >= 0.00392156862745098f) ? fminf(al, 0.999f) : 0.f;  // exact cull
    float wgt = al * T;
    accr = fmaf(wgt, b.z, accr);
    accg = fmaf(wgt, b.w, accg);
    accb = fmaf(wgt, c.x, accb);
    acca += wgt;
    T *= 1.f - al;
  }
  red[w][0][lane] = accr;
  red[w][1][lane] = accg;
  red[w][2][lane] = accb;
  red[w][3][lane] = acca;
  red[w][4][lane] = T;
  __syncthreads();

  // ---- exact combine across the 8 ordered segments ----
  if (t < 64) {
    float Tr = 1.f, R = 0.f, G = 0.f, B = 0.f, A = 0.f;
#pragma unroll
    for (int k = 0; k < 8; ++k) {
      R += Tr * red[k][0][t];
      G += Tr * red[k][1][t];
      B += Tr * red[k][2][t];
      A += Tr * red[k][3][t];
      Tr *= red[k][4][t];
    }
    int pix = (ty * 8 + (t >> 3)) * Wimg + tx * 8 + (t & 7);
    out[pix * 3 + 0] = R;
    out[pix * 3 + 1] = G;
    out[pix * 3 + 2] = B;
    out[(size_t)P * 3 + pix] = A;
  }
}

extern "C" void kernel_launch(void* const* d_in, const int* in_sizes, int n_in,
                              void* d_out, int out_size, void* d_ws, size_t ws_size,
                              hipStream_t stream) {
  const float* means  = (const float*)d_in[0];
  const float* quats  = (const float*)d_in[1];
  const float* scales = (const float*)d_in[2];
  const float* opacs  = (const float*)d_in[3];
  const float* colors = (const float*)d_in[4];
  const float* ct     = (const float*)d_in[5];
  const float* Kmat   = (const float*)d_in[6];

  int N = in_sizes[0] / 3;       // means is (N,3)
  int P = out_size / 4;          // 3*H*W colors + H*W alphas
  int Wimg = 128;                // harness-fixed (W==H, P=W*H)
  int Himg = P / Wimg;
  int tilesX = Wimg / 8, tilesY = Himg / 8;

  float*  pre  = (float*)d_ws;                        // 11*N floats
  float*  srt  = pre + (size_t)11 * N;                // 12*N floats (48B AoS)
  float4* bbox = (float4*)(srt + (size_t)12 * N);     // N float4
  int*    rank = (int*)(bbox + N);                    // N ints

  int nb = (N + 255) / 256;
  k_pre<<<nb, 256, 0, stream>>>(means, quats, scales, opacs, colors, ct, Kmat, N, pre, rank);
  dim3 rg(nb, 32);
  k_rank<<<rg, 256, 0, stream>>>(pre, N, rank);
  k_scatter<<<nb, 256, 0, stream>>>(pre, N, rank, srt, bbox);
  k_render<<<tilesX * tilesY, 512, 0, stream>>>(srt, bbox, N, (float*)d_out, Wimg, tilesX, P);
}